// Round 5
// baseline (255.454 us; speedup 1.0000x reference)
//
#include <hip/hip_runtime.h>
#include <math.h>

#define NPTS 16384
#define HDIM 64
#define JCH 32
#define CHUNK (NPTS / JCH)   // 512
#define IBLK 256
#define NIB (NPTS / IBLK)    // 64 i-groups; grid = 64*32 = 2048 blocks (8/CU)
#define EPSF 1e-8f
#define FMAX3 3.402823466e38f

// keep-2-smallest insert (m1<=m2). m2 reads OLD m1 -> order matters.
__device__ __forceinline__ void ins2(float& m1, float& m2, float d) {
    m2 = __builtin_amdgcn_fmed3f(d, m1, m2);
    m1 = fminf(d, m1);
}

// Single fused kernel. Block b: ic = b>>5 (i-group of 256), jc = b&31 (j-chunk).
// Phase 1: 2 smallest cross |xi-xj| over chunk jc (blockIdx-derived jc ->
//   provably uniform base -> s_load scalar pipe; 3 VALU ops/pair). Diagonal
//   chunk (block-uniform: jc == ic>>1) tracks top-3, drops the self-zero.
// Phase 2 (32nd finisher of group ic via ticket): merge 32 partials -> dens;
//   MLP fwd + analytic d2y/dx2; block-reduce -> slot[ic].
// Phase 3 (64th group-finisher): sum slots, finalize out[0..2].
__global__ __launch_bounds__(IBLK, 8) void fused_kernel(
    const float* __restrict__ x, const float* __restrict__ tg,
    const float* __restrict__ w1, const float* __restrict__ b1,
    const float* __restrict__ w2, const float* __restrict__ b2,
    float2* __restrict__ part, unsigned int* __restrict__ gticket,
    unsigned int* __restrict__ fticket, float4* __restrict__ slot,
    float* __restrict__ out) {
    const int jc = blockIdx.x & (JCH - 1);
    const int ic = blockIdx.x >> 5;
    const int t = threadIdx.x;
    const int i = ic * IBLK + t;
    const float xi = x[i];
    const float* __restrict__ xc = x + jc * CHUNK;  // uniform base -> s_load

    float m1 = FMAX3, m2 = FMAX3;
    if (jc == (ic >> 1)) {           // block-uniform: diagonal chunk (has j==i)
        float m3 = FMAX3;
#pragma unroll 16
        for (int k = 0; k < CHUNK; ++k) {
            float d = fabsf(xi - xc[k]);
            m3 = __builtin_amdgcn_fmed3f(d, m2, m3);
            m2 = __builtin_amdgcn_fmed3f(d, m1, m2);
            m1 = fminf(d, m1);
        }
        m1 = m2;                     // drop self-zero (rank-1 in this chunk)
        m2 = m3;
    } else {
#pragma unroll 16
        for (int k = 0; k < CHUNK; ++k) {
            float d = fabsf(xi - xc[k]);
            ins2(m1, m2, d);
        }
    }
    part[jc * NPTS + i] = make_float2(m1, m2);  // coalesced 8B/lane

    // ---- ticket: classic threadfence-reduction pattern (device scope) ----
    __shared__ unsigned int s_tick;
    __threadfence();
    __syncthreads();
    if (t == 0) s_tick = atomicAdd(&gticket[ic], 1u);
    __syncthreads();
    if (s_tick != JCH - 1) return;   // block-uniform exit

    // ---- phase 2: this block is the last of group ic ----
    __threadfence();                 // acquire: other blocks' part stores
    float M1 = FMAX3, M2 = FMAX3;
#pragma unroll
    for (int jj = 0; jj < JCH; ++jj) {
        float2 p = part[jj * NPTS + i];
        ins2(M1, M2, p.x);
        ins2(M1, M2, p.y);
    }
    // reference knn row = [EPS(self), d1+EPS, d2+EPS]; mean+EPS = (d1+d2)/3+2EPS
    float dens = 1.0f / ((M1 + M2) * (1.0f / 3.0f) + 2.0f * EPSF);

    float y = b2[0];
    float d2a = 0.0f;
#pragma unroll 4
    for (int j = 0; j < HDIM; ++j) {
        float a1 = w1[j], bb = b1[j], a2 = w2[j];   // uniform -> scalar loads
        float u = fmaf(xi, a1, bb);
        float e = __expf(2.0f * u);
        float r = __builtin_amdgcn_rcpf(e + 1.0f);
        float tt = fmaf(-2.0f, r, 1.0f);            // tanh(u)
        y = fmaf(a2, tt, y);
        float g = 2.0f * tt * fmaf(tt, tt, -1.0f);  // -2 t (1 - t^2)
        d2a = fmaf(a2 * a1 * a1, g, d2a);
    }
    float diff = y - tg[i];
    float rs_mse = diff * diff;
    float rs_d2 = d2a * d2a;
    float rs_dn = dens, rmx = dens;
    for (int o = 32; o > 0; o >>= 1) {
        rs_mse += __shfl_down(rs_mse, o);
        rs_d2 += __shfl_down(rs_d2, o);
        rs_dn += __shfl_down(rs_dn, o);
        rmx = fmaxf(rmx, __shfl_down(rmx, o));
    }
    __shared__ float red[4][4];
    const int wv = t >> 6, ln = t & 63;
    if (ln == 0) {
        red[0][wv] = rs_mse;
        red[1][wv] = rs_d2;
        red[2][wv] = rs_dn;
        red[3][wv] = rmx;
    }
    __syncthreads();
    if (t == 0) {
        float a0 = red[0][0] + red[0][1] + red[0][2] + red[0][3];
        float a1 = red[1][0] + red[1][1] + red[1][2] + red[1][3];
        float a2 = red[2][0] + red[2][1] + red[2][2] + red[2][3];
        float am = fmaxf(fmaxf(red[3][0], red[3][1]), fmaxf(red[3][2], red[3][3]));
        slot[ic] = make_float4(a0, a1, a2, am);
        __threadfence();
        unsigned int ft = atomicAdd(fticket, 1u);
        if (ft == NIB - 1) {
            // ---- phase 3: final group -> finalize out ----
            __threadfence();
            float s0 = 0.0f, s1 = 0.0f, s2 = 0.0f, mx = 0.0f;
#pragma unroll 8
            for (int g = 0; g < NIB; ++g) {
                float4 v = slot[g];
                s0 += v.x;
                s1 += v.y;
                s2 += v.z;
                mx = fmaxf(mx, v.w);
            }
            float mse = s0 * (1.0f / NPTS);
            float md2 = s1 * (1.0f / NPTS);
            float mean_density = (s2 * (1.0f / NPTS)) / (mx + EPSF);
            float penalty = 0.01f * (1.0f + 0.1f * mean_density) * md2;
            out[0] = mse + penalty;
            out[1] = mse;
            out[2] = penalty;
        }
    }
}

extern "C" void kernel_launch(void* const* d_in, const int* in_sizes, int n_in,
                              void* d_out, int out_size, void* d_ws, size_t ws_size,
                              hipStream_t stream) {
    const float* x = (const float*)d_in[0];
    const float* tg = (const float*)d_in[1];
    const float* w1 = (const float*)d_in[2];
    const float* b1 = (const float*)d_in[3];
    const float* w2 = (const float*)d_in[4];
    const float* b2 = (const float*)d_in[5];
    float* out = (float*)d_out;
    float* wsf = (float*)d_ws;

    float2* part = (float2*)wsf;                            // 4 MB
    unsigned int* gticket = (unsigned int*)(wsf + 2 * JCH * NPTS);  // 64 uints
    unsigned int* fticket = gticket + NIB;                  // 1 uint
    float4* slot = (float4*)(gticket + NIB + 4);            // 16B-aligned, 64 float4

    // zero only the tickets (260 B) — cannot rely on ws poison value
    hipMemsetAsync(gticket, 0, (NIB + 4) * sizeof(unsigned int), stream);
    hipLaunchKernelGGL(fused_kernel, dim3(NIB * JCH), dim3(IBLK), 0, stream,
                       x, tg, w1, b1, w2, b2, part, gticket, fticket, slot, out);
}

// Round 6
// 105.048 us; speedup vs baseline: 2.4318x; 2.4318x over previous
//
#include <hip/hip_runtime.h>
#include <math.h>

#define NPTS 16384
#define HDIM 64
#define JCH 32
#define CHUNK (NPTS / JCH)   // 512
#define IBLK 256
#define NIB (NPTS / IBLK)    // 64 i-blocks; grid1 = 64*32 = 2048 blocks (8/CU)
#define EPSF 1e-8f
#define FMAX3 3.402823466e38f

// keep-2-smallest insert (m1<=m2). m2 reads OLD m1 -> order matters.
__device__ __forceinline__ void ins2(float& m1, float& m2, float d) {
    m2 = __builtin_amdgcn_fmed3f(d, m1, m2);
    m1 = fminf(d, m1);
}

// Kernel 1: per (i-block, j-chunk): 2 smallest cross |xi-xj| over the chunk.
// jc comes from blockIdx -> PROVABLY uniform -> scalar s_load on SMEM pipe
// (R3 lesson: threadIdx-derived chunk index kills this; R5 lesson: do NOT
// fuse the merge via device-scope fences — 2048 L2-writeback fences cost
// ~100 µs; the kernel boundary is the free sync). 3 VALU ops/pair.
// Diagonal chunk (contains j==i) is block-uniform: jc == (ic>>1). It tracks
// top-3 and drops the self-zero. Block 0 also zeroes the accumulators for
// kernel 2 (cross-dispatch visibility validated in R2).
__global__ __launch_bounds__(IBLK) void knn2_kernel(
    const float* __restrict__ x, float2* __restrict__ part,
    float* __restrict__ acc) {
    const int jc = blockIdx.x & (JCH - 1);
    const int ic = blockIdx.x >> 5;
    if (blockIdx.x == 0 && threadIdx.x < 8) acc[threadIdx.x] = 0.0f;
    const int i = ic * IBLK + threadIdx.x;
    const float xi = x[i];
    const float* __restrict__ xc = x + jc * CHUNK;  // uniform base -> s_load

    float m1 = FMAX3, m2 = FMAX3;
    if (jc == (ic >> 1)) {           // block-uniform branch: diagonal chunk
        float m3 = FMAX3;
#pragma unroll 16
        for (int k = 0; k < CHUNK; ++k) {
            float d = fabsf(xi - xc[k]);
            m3 = __builtin_amdgcn_fmed3f(d, m2, m3);
            m2 = __builtin_amdgcn_fmed3f(d, m1, m2);
            m1 = fminf(d, m1);
        }
        m1 = m2;                     // drop self-zero (rank-1 in this chunk)
        m2 = m3;
    } else {
#pragma unroll 16
        for (int k = 0; k < CHUNK; ++k) {
            float d = fabsf(xi - xc[k]);
            ins2(m1, m2, d);
        }
    }
    part[jc * NPTS + i] = make_float2(m1, m2);  // coalesced 8B/lane
}

// Kernel 2: merge 32 partial pairs -> dens_i; MLP fwd + analytic d2y/dx2;
// wave-reduce, atomic-accumulate, last block finalizes out[0..2].
// Reference: diff = |xi-xj| + EPS incl. self (=EPS); knn=[EPS,d1+EPS,d2+EPS];
// mean+EPS = (d1+d2)/3 + 2*EPS.
__global__ __launch_bounds__(64) void merge_kernel(
    const float* __restrict__ x, const float* __restrict__ tg,
    const float* __restrict__ w1, const float* __restrict__ b1,
    const float* __restrict__ w2, const float* __restrict__ b2,
    const float2* __restrict__ part, float* __restrict__ acc,
    float* __restrict__ out) {
    const int t = threadIdx.x;       // block = one wave
    const int i = blockIdx.x * 64 + t;

    float m1 = FMAX3, m2 = FMAX3;
#pragma unroll
    for (int jc = 0; jc < JCH; ++jc) {
        float2 p = part[jc * NPTS + i];
        ins2(m1, m2, p.x);
        ins2(m1, m2, p.y);
    }
    float dens = 1.0f / ((m1 + m2) * (1.0f / 3.0f) + 2.0f * EPSF);

    const float xi = x[i];
    float y = b2[0];
    float d2a = 0.0f;
#pragma unroll 8
    for (int j = 0; j < HDIM; ++j) {
        float a1 = w1[j], bb = b1[j], a2 = w2[j];   // uniform -> scalar loads
        float u = fmaf(xi, a1, bb);
        float e = __expf(2.0f * u);
        float r = __builtin_amdgcn_rcpf(e + 1.0f);
        float tt = fmaf(-2.0f, r, 1.0f);            // tanh(u)
        y = fmaf(a2, tt, y);
        float g = 2.0f * tt * fmaf(tt, tt, -1.0f);  // -2 t (1 - t^2)
        d2a = fmaf(a2 * a1 * a1, g, d2a);
    }
    float diff = y - tg[i];
    float rs_mse = diff * diff;
    float rs_d2 = d2a * d2a;
    float rs_dn = dens, rmx = dens;
    for (int o = 32; o > 0; o >>= 1) {
        rs_mse += __shfl_down(rs_mse, o);
        rs_d2 += __shfl_down(rs_d2, o);
        rs_dn += __shfl_down(rs_dn, o);
        rmx = fmaxf(rmx, __shfl_down(rmx, o));
    }
    if (t == 0) {
        atomicAdd(&acc[0], rs_mse);
        atomicAdd(&acc[1], rs_d2);
        atomicAdd(&acc[2], rs_dn);
        atomicMax((unsigned int*)&acc[3], __float_as_uint(rmx));  // dens>0: uint order == float order
        __threadfence();
        unsigned int ticket = atomicAdd((unsigned int*)&acc[4], 1u);
        if (ticket == (NPTS / 64) - 1) {
            float s_mse = atomicAdd(&acc[0], 0.0f);
            float s_d2 = atomicAdd(&acc[1], 0.0f);
            float s_dn = atomicAdd(&acc[2], 0.0f);
            float dmax = __uint_as_float(atomicMax((unsigned int*)&acc[3], 0u));
            float mse = s_mse * (1.0f / NPTS);
            float md2 = s_d2 * (1.0f / NPTS);
            float mean_density = (s_dn * (1.0f / NPTS)) / (dmax + EPSF);
            float penalty = 0.01f * (1.0f + 0.1f * mean_density) * md2;
            out[0] = mse + penalty;
            out[1] = mse;
            out[2] = penalty;
        }
    }
}

extern "C" void kernel_launch(void* const* d_in, const int* in_sizes, int n_in,
                              void* d_out, int out_size, void* d_ws, size_t ws_size,
                              hipStream_t stream) {
    const float* x = (const float*)d_in[0];
    const float* tg = (const float*)d_in[1];
    const float* w1 = (const float*)d_in[2];
    const float* b1 = (const float*)d_in[3];
    const float* w2 = (const float*)d_in[4];
    const float* b2 = (const float*)d_in[5];
    float* out = (float*)d_out;
    float* wsf = (float*)d_ws;
    float2* part = (float2*)wsf;             // JCH*NPTS float2 = 4 MB
    float* acc = wsf + 2 * JCH * NPTS;       // 4 accumulators + ticket (zeroed by knn2)

    hipLaunchKernelGGL(knn2_kernel, dim3(NIB * JCH), dim3(IBLK), 0, stream, x, part, acc);
    hipLaunchKernelGGL(merge_kernel, dim3(NPTS / 64), dim3(64), 0, stream,
                       x, tg, w1, b1, w2, b2, part, acc, out);
}